// Round 1
// baseline (2715.200 us; speedup 1.0000x reference)
//
#include <hip/hip_runtime.h>
#include <cstddef>

// Problem: GCN-LSTM decoder. N=50000 nodes, E=600000 edges, H=O=128, S=8.
// Restructure: GCN(feat,W,b) = (A_norm@feat)@W + b  (aggregation is linear).
// combined=[x,h] => A@combined = [A@x, A@h]; A@x precomputed once.
// Per step: cc = ax@W[:128] + ah@W[128:] + b, gates fused into GEMM epilogue.

#define TPB 256

__device__ __forceinline__ float sigf(float x) {
    return 1.0f / (1.0f + __expf(-x));
}
__device__ __forceinline__ float tanhfast(float x) {
    // 1 - 2/(e^{2x}+1): exact at +-inf, ~1e-6 rel error
    return 1.0f - 2.0f / (__expf(2.0f * x) + 1.0f);
}

// ---------------- CSR build ----------------

__global__ void k_hist(const int* __restrict__ dst, int* __restrict__ counts, int E) {
    int e = blockIdx.x * TPB + threadIdx.x;
    if (e < E) atomicAdd(&counts[dst[e]], 1);
}

__global__ void k_scan_block(const int* __restrict__ counts, int* __restrict__ offsets,
                             int* __restrict__ sums, int N) {
    __shared__ int s[TPB];
    int tid = threadIdx.x;
    int gid = blockIdx.x * TPB + tid;
    int v = (gid < N) ? counts[gid] : 0;
    s[tid] = v;
    __syncthreads();
    for (int d = 1; d < TPB; d <<= 1) {
        int t = (tid >= d) ? s[tid - d] : 0;
        __syncthreads();
        s[tid] += t;
        __syncthreads();
    }
    if (gid < N) offsets[gid] = s[tid] - v;   // exclusive within block
    if (tid == TPB - 1) sums[blockIdx.x] = s[tid];
}

__global__ void k_scan_tops(int* __restrict__ sums, int nb) {
    __shared__ int s[TPB];
    int tid = threadIdx.x;
    int v = (tid < nb) ? sums[tid] : 0;
    s[tid] = v;
    __syncthreads();
    for (int d = 1; d < TPB; d <<= 1) {
        int t = (tid >= d) ? s[tid - d] : 0;
        __syncthreads();
        s[tid] += t;
        __syncthreads();
    }
    if (tid < nb) sums[tid] = s[tid] - v;     // exclusive block offsets
}

__global__ void k_scan_finish(const int* __restrict__ counts, int* __restrict__ offsets,
                              const int* __restrict__ sums, int* __restrict__ cursor,
                              float* __restrict__ dinv, int N, int E) {
    int gid = blockIdx.x * TPB + threadIdx.x;
    if (gid < N) {
        int off = offsets[gid] + sums[blockIdx.x];
        offsets[gid] = off;
        cursor[gid]  = off;
        dinv[gid]    = rsqrtf((float)(counts[gid] + 1));  // deg includes self-loop
    }
    if (gid == 0) offsets[N] = E;
}

__global__ void k_csr_scatter(const int* __restrict__ src, const int* __restrict__ dst,
                              const float* __restrict__ dinv, int* __restrict__ cursor,
                              int* __restrict__ csr_src, float* __restrict__ csr_w, int E) {
    int e = blockIdx.x * TPB + threadIdx.x;
    if (e >= E) return;
    int d = dst[e], s = src[e];
    int pos = atomicAdd(&cursor[d], 1);
    csr_src[pos] = s;
    csr_w[pos] = dinv[s] * dinv[d];
}

// ---------------- aggregation: agg = A_norm @ feat  (feat [N,128]) ----------------
// One wave per node; lane holds 2 channels (float2). Gather-based, no atomics.

__global__ __launch_bounds__(TPB) void k_aggregate(
        const float* __restrict__ feat, float* __restrict__ agg,
        const int* __restrict__ offsets, const int* __restrict__ csr_src,
        const float* __restrict__ csr_w, const float* __restrict__ dinv, int N) {
    int node = blockIdx.x * 4 + (threadIdx.x >> 6);
    if (node >= N) return;
    int lane = threadIdx.x & 63;
    const float2* f2 = (const float2*)feat;
    float2 self = f2[(size_t)node * 64 + lane];
    float di = dinv[node];
    float w0 = di * di;
    float accx = w0 * self.x, accy = w0 * self.y;
    int b = offsets[node], e = offsets[node + 1];
    for (int k = b; k < e; ++k) {
        int s = csr_src[k];
        float w = csr_w[k];
        float2 v = f2[(size_t)s * 64 + lane];
        accx = fmaf(w, v.x, accx);
        accy = fmaf(w, v.y, accy);
    }
    float2 r; r.x = accx; r.y = accy;
    ((float2*)agg)[(size_t)node * 64 + lane] = r;
}

// ---------------- GEMM: C[N,128] = A[N,128] @ W[128,128] + b ----------------
// Block: 32 rows x 128 cols, 256 threads, each thread 4x4.

__global__ __launch_bounds__(TPB) void k_gemm_bias(
        const float* __restrict__ A, const float* __restrict__ W,
        const float* __restrict__ bias, float* __restrict__ Cout, int N) {
    __shared__ __align__(16) float As[16][36];
    __shared__ __align__(16) float Bs[16][128];
    int tid = threadIdx.x;
    int tx = tid & 31, ty = tid >> 5;
    int r0 = blockIdx.x * 32;
    float acc[4][4] = {};
    for (int kt = 0; kt < 8; ++kt) {
        for (int i = 0; i < 2; ++i) {
            int lin = i * TPB + tid;
            int k = lin & 15, r = lin >> 4;
            int row = r0 + r;
            float v = 0.0f;
            if (row < N) v = A[(size_t)row * 128 + kt * 16 + k];
            As[k][r] = v;
        }
        for (int i = 0; i < 8; ++i) {
            int lin = i * TPB + tid;
            int col = lin & 127, k = lin >> 7;
            Bs[k][col] = W[(size_t)(kt * 16 + k) * 128 + col];
        }
        __syncthreads();
        #pragma unroll
        for (int k = 0; k < 16; ++k) {
            float a[4], bv[4];
            #pragma unroll
            for (int r = 0; r < 4; ++r) a[r] = As[k][ty * 4 + r];
            #pragma unroll
            for (int g = 0; g < 4; ++g) bv[g] = Bs[k][tx + 32 * g];
            #pragma unroll
            for (int r = 0; r < 4; ++r)
                #pragma unroll
                for (int g = 0; g < 4; ++g)
                    acc[r][g] = fmaf(a[r], bv[g], acc[r][g]);
        }
        __syncthreads();
    }
    #pragma unroll
    for (int r = 0; r < 4; ++r) {
        int row = r0 + ty * 4 + r;
        if (row < N) {
            #pragma unroll
            for (int g = 0; g < 4; ++g) {
                int col = tx + 32 * g;
                Cout[(size_t)row * 128 + col] = acc[r][g] + bias[col];
            }
        }
    }
}

// ---------------- fused cell GEMM + LSTM gates ----------------
// cc[N,512] = ax@W[:128,:] + ah@W[128:,:] + b ; gates in epilogue.
// Block: 32 rows x (32 cols x 4 gates), grid.y = 4 col-chunks.

__global__ __launch_bounds__(TPB) void k_gemm_cell(
        const float* __restrict__ Ax, const float* __restrict__ Ah,
        const float* __restrict__ W, const float* __restrict__ bias,
        float* __restrict__ cbuf, float* __restrict__ hout,
        float* __restrict__ hfin, int N) {
    __shared__ __align__(16) float As[16][36];
    __shared__ __align__(16) float Bs[16][132];   // Bs[k][jj*4+g]
    int tid = threadIdx.x;
    int tx = tid & 31, ty = tid >> 5;
    int r0 = blockIdx.x * 32;
    int j0 = blockIdx.y * 32;
    float acc[4][4] = {};
    for (int kt = 0; kt < 16; ++kt) {
        const float* Ap = (kt < 8) ? Ax : Ah;
        int kbase = (kt & 7) * 16;
        for (int i = 0; i < 2; ++i) {
            int lin = i * TPB + tid;
            int k = lin & 15, r = lin >> 4;
            int row = r0 + r;
            float v = 0.0f;
            if (row < N) v = Ap[(size_t)row * 128 + kbase + k];
            As[k][r] = v;
        }
        for (int i = 0; i < 8; ++i) {
            int lin = i * TPB + tid;
            int col = lin & 127, k = lin >> 7;
            int g = col >> 5, jj = col & 31;
            Bs[k][jj * 4 + g] = W[(size_t)(kt * 16 + k) * 512 + g * 128 + j0 + jj];
        }
        __syncthreads();
        #pragma unroll
        for (int k = 0; k < 16; ++k) {
            float a[4], bv[4];
            #pragma unroll
            for (int r = 0; r < 4; ++r) a[r] = As[k][ty * 4 + r];
            #pragma unroll
            for (int g = 0; g < 4; ++g) bv[g] = Bs[k][tx * 4 + g];
            #pragma unroll
            for (int r = 0; r < 4; ++r)
                #pragma unroll
                for (int g = 0; g < 4; ++g)
                    acc[r][g] = fmaf(a[r], bv[g], acc[r][g]);
        }
        __syncthreads();
    }
    int col = j0 + tx;
    float bf = bias[col], bi = bias[128 + col], bo = bias[256 + col], bg = bias[384 + col];
    #pragma unroll
    for (int r = 0; r < 4; ++r) {
        int row = r0 + ty * 4 + r;
        if (row < N) {
            float f = sigf(acc[r][0] + bf);
            float i = sigf(acc[r][1] + bi);
            float o = sigf(acc[r][2] + bo);
            float g = tanhfast(acc[r][3] + bg);
            size_t idx = (size_t)row * 128 + col;
            float cp = cbuf[idx];
            float cn = fmaf(f, cp, i * g);
            cbuf[idx] = cn;
            float hn = o * tanhfast(cn);
            hout[idx] = hn;
            if (hfin) hfin[idx] = hn;
        }
    }
}

// ---------------- launch ----------------

extern "C" void kernel_launch(void* const* d_in, const int* in_sizes, int n_in,
                              void* d_out, int out_size, void* d_ws, size_t ws_size,
                              hipStream_t stream) {
    const float* x  = (const float*)d_in[0];
    const float* c  = (const float*)d_in[1];
    const int*   ei = (const int*)d_in[2];
    const float* Wh = (const float*)d_in[3];
    const float* bh = (const float*)d_in[4];
    const float* Wc = (const float*)d_in[5];
    const float* bc = (const float*)d_in[6];
    const float* Wcell = (const float*)d_in[7];
    const float* bcell = (const float*)d_in[8];
    float* out = (float*)d_out;

    const int N = in_sizes[0] / 128;
    const int E = in_sizes[2] / 2;
    const int S = in_sizes[7] / (256 * 512);
    const int* srcp = ei;
    const int* dstp = ei + E;

    // output layout: hs [S,N,128] | h_fin [N,128] | c_fin [N,128]
    float* hs   = out;
    float* hfin = out + (size_t)S * N * 128;
    float* cbuf = hfin + (size_t)N * 128;   // running c, final value = c_fin

    // workspace bump allocator (256B aligned)
    char* w = (char*)d_ws;
    size_t off = 0;
    auto alloc = [&](size_t bytes) -> void* {
        void* p = w + off;
        off += (bytes + 255) & ~(size_t)255;
        return p;
    };
    int*   counts  = (int*)alloc((size_t)N * 4);
    int*   offsets = (int*)alloc((size_t)(N + 1) * 4);
    int*   cursor  = (int*)alloc((size_t)N * 4);
    int*   sums    = (int*)alloc(256 * 4);
    int*   csr_src = (int*)alloc((size_t)E * 4);
    float* csr_w   = (float*)alloc((size_t)E * 4);
    float* dinv    = (float*)alloc((size_t)N * 4);
    float* ax      = (float*)alloc((size_t)N * 128 * 4);
    float* aag     = (float*)alloc((size_t)N * 128 * 4);  // ac, then ah per step
    float* h0      = (float*)alloc((size_t)N * 128 * 4);
    (void)ws_size; (void)n_in; (void)out_size;

    hipMemsetAsync(counts, 0, (size_t)N * 4, stream);
    int eblk = (E + TPB - 1) / TPB;
    int nb   = (N + TPB - 1) / TPB;
    k_hist<<<eblk, TPB, 0, stream>>>(dstp, counts, E);
    k_scan_block<<<nb, TPB, 0, stream>>>(counts, offsets, sums, N);
    k_scan_tops<<<1, TPB, 0, stream>>>(sums, nb);
    k_scan_finish<<<nb, TPB, 0, stream>>>(counts, offsets, sums, cursor, dinv, N, E);
    k_csr_scatter<<<eblk, TPB, 0, stream>>>(srcp, dstp, dinv, cursor, csr_src, csr_w, E);

    int nagg = (N + 3) / 4;
    int ngb  = (N + 31) / 32;
    k_aggregate<<<nagg, TPB, 0, stream>>>(x, ax, offsets, csr_src, csr_w, dinv, N);
    k_aggregate<<<nagg, TPB, 0, stream>>>(c, aag, offsets, csr_src, csr_w, dinv, N);
    k_gemm_bias<<<ngb, TPB, 0, stream>>>(ax, Wh, bh, h0, N);
    k_gemm_bias<<<ngb, TPB, 0, stream>>>(aag, Wc, bc, cbuf, N);

    for (int s = 0; s < S; ++s) {
        const float* hprev = (s == 0) ? h0 : hs + (size_t)(s - 1) * N * 128;
        k_aggregate<<<nagg, TPB, 0, stream>>>(hprev, aag, offsets, csr_src, csr_w, dinv, N);
        k_gemm_cell<<<dim3(ngb, 4), TPB, 0, stream>>>(
            ax, aag, Wcell + (size_t)s * 256 * 512, bcell + (size_t)s * 512,
            cbuf, hs + (size_t)s * N * 128, (s == S - 1) ? hfin : nullptr, N);
    }
}

// Round 2
// 1645.909 us; speedup vs baseline: 1.6497x; 1.6497x over previous
//
#include <hip/hip_runtime.h>
#include <hip/hip_bf16.h>
#include <cstddef>

// GCN-LSTM decoder, N=50000, E=600000, H=O=128, S=8.
// GCN(feat,W,b) = (A_norm@feat)@W + b  (aggregate first, then GEMM).
// combined=[x,h] => A@combined = [A@x, A@h]; A@x precomputed once.
// GEMMs in bf16 MFMA (16x16x32), computed TRANSPOSED: C'[p][node], where for
// the cell GEMM p = jcol*4 + gate so one lane's 4 acc regs = the 4 LSTM gates
// of one (node, jcol) -> fused epilogue with no cross-lane traffic.

#define TPB 256

typedef __attribute__((ext_vector_type(8))) short bf16x8;   // 8 bf16 = 4 VGPR
typedef __attribute__((ext_vector_type(4))) float f32x4;

__device__ __forceinline__ float sigf(float x) {
    return 1.0f / (1.0f + __expf(-x));
}
__device__ __forceinline__ float tanhfast(float x) {
    return 1.0f - 2.0f / (__expf(2.0f * x) + 1.0f);
}

// ---------------- CSR build ----------------

__global__ void k_hist(const int* __restrict__ dst, int* __restrict__ counts, int E) {
    int e = blockIdx.x * TPB + threadIdx.x;
    if (e < E) atomicAdd(&counts[dst[e]], 1);
}

__global__ void k_scan_block(const int* __restrict__ counts, int* __restrict__ offsets,
                             int* __restrict__ sums, int N) {
    __shared__ int s[TPB];
    int tid = threadIdx.x;
    int gid = blockIdx.x * TPB + tid;
    int v = (gid < N) ? counts[gid] : 0;
    s[tid] = v;
    __syncthreads();
    for (int d = 1; d < TPB; d <<= 1) {
        int t = (tid >= d) ? s[tid - d] : 0;
        __syncthreads();
        s[tid] += t;
        __syncthreads();
    }
    if (gid < N) offsets[gid] = s[tid] - v;
    if (tid == TPB - 1) sums[blockIdx.x] = s[tid];
}

__global__ void k_scan_tops(int* __restrict__ sums, int nb) {
    __shared__ int s[TPB];
    int tid = threadIdx.x;
    int v = (tid < nb) ? sums[tid] : 0;
    s[tid] = v;
    __syncthreads();
    for (int d = 1; d < TPB; d <<= 1) {
        int t = (tid >= d) ? s[tid - d] : 0;
        __syncthreads();
        s[tid] += t;
        __syncthreads();
    }
    if (tid < nb) sums[tid] = s[tid] - v;
}

__global__ void k_scan_finish(const int* __restrict__ counts, int* __restrict__ offsets,
                              const int* __restrict__ sums, int* __restrict__ cursor,
                              float* __restrict__ dinv, int N, int E) {
    int gid = blockIdx.x * TPB + threadIdx.x;
    if (gid < N) {
        int off = offsets[gid] + sums[blockIdx.x];
        offsets[gid] = off;
        cursor[gid]  = off;
        dinv[gid]    = rsqrtf((float)(counts[gid] + 1));
    }
    if (gid == 0) offsets[N] = E;
}

__global__ void k_csr_scatter(const int* __restrict__ src, const int* __restrict__ dst,
                              const float* __restrict__ dinv, int* __restrict__ cursor,
                              int* __restrict__ csr_src, float* __restrict__ csr_w, int E) {
    int e = blockIdx.x * TPB + threadIdx.x;
    if (e >= E) return;
    int d = dst[e], s = src[e];
    int pos = atomicAdd(&cursor[d], 1);
    csr_src[pos] = s;
    csr_w[pos] = dinv[s] * dinv[d];
}

// ---------------- aggregation: agg(bf16) = A_norm @ feat(fp32) ----------------
// One wave per node; lane holds 2 channels.

__global__ __launch_bounds__(TPB) void k_aggregate_b(
        const float* __restrict__ feat, __hip_bfloat16* __restrict__ agg,
        const int* __restrict__ offsets, const int* __restrict__ csr_src,
        const float* __restrict__ csr_w, const float* __restrict__ dinv, int N) {
    int node = blockIdx.x * 4 + (threadIdx.x >> 6);
    if (node >= N) return;
    int lane = threadIdx.x & 63;
    const float2* f2 = (const float2*)feat;
    float2 self = f2[(size_t)node * 64 + lane];
    float di = dinv[node];
    float w0 = di * di;
    float accx = w0 * self.x, accy = w0 * self.y;
    int b = offsets[node], e = offsets[node + 1];
    for (int k = b; k < e; ++k) {
        int s = csr_src[k];
        float w = csr_w[k];
        float2 v = f2[(size_t)s * 64 + lane];
        accx = fmaf(w, v.x, accx);
        accy = fmaf(w, v.y, accy);
    }
    __hip_bfloat162 r;
    r.x = __float2bfloat16(accx);
    r.y = __float2bfloat16(accy);
    ((__hip_bfloat162*)agg)[(size_t)node * 64 + lane] = r;
}

// ---------------- weight packing into MFMA A-frag order ----------------
// Layout: Wp[ks][pblk][lane][j] = W'[pblk*16 + (lane&15)][ks*32 + (lane>>4)*8 + j]

__global__ void k_pack_w128(const float* __restrict__ W, __hip_bfloat16* __restrict__ Wp) {
    int idx = blockIdx.x * TPB + threadIdx.x;     // 4*8*64*8 = 16384
    if (idx >= 16384) return;
    int j = idx & 7, lane = (idx >> 3) & 63, pblk = (idx >> 9) & 7, ks = idx >> 12;
    int k = ks * 32 + (lane >> 4) * 8 + j;
    int col = pblk * 16 + (lane & 15);
    Wp[idx] = __float2bfloat16(W[k * 128 + col]);
}

// cell weights: p = jcol*4 + gate  (gate order f,i,o,g matches bcell blocks)
__global__ void k_pack_wcell(const float* __restrict__ W, __hip_bfloat16* __restrict__ Wp, int S) {
    int idx = blockIdx.x * TPB + threadIdx.x;     // S * 8*32*64*8 = S*131072
    if (idx >= S * 131072) return;
    int j = idx & 7, lane = (idx >> 3) & 63, pblk = (idx >> 9) & 31;
    int ks = (idx >> 14) & 7, s = idx >> 17;
    int p = pblk * 16 + (lane & 15);
    int jcol = p >> 2, gate = p & 3;
    int k = ks * 32 + (lane >> 4) * 8 + j;
    Wp[idx] = __float2bfloat16(W[(size_t)s * 131072 + k * 512 + gate * 128 + jcol]);
}

// ---------------- transposed MFMA GEMM: C[node][128] = agg @ W + b ----------------
// M = 128 weight cols (p), N-dim = nodes. Block: 128p x 128nodes, 4 waves 2x2.

__global__ __launch_bounds__(TPB) void k_gemm_t(
        const __hip_bfloat16* __restrict__ Ap,     // packed [4][8][64][8]
        const __hip_bfloat16* __restrict__ featb,  // [N][128] bf16
        const float* __restrict__ bias, float* __restrict__ Cout, int N) {
    __shared__ __align__(16) short Bs[128 * 40];   // 128 nodes x 32 bf16, stride 40
    int tid = threadIdx.x;
    int wave = tid >> 6, lane = tid & 63;
    int w_p = wave >> 1, w_n = wave & 1;
    int n0 = blockIdx.x * 128;
    int quad = lane >> 4, m16 = lane & 15;
    f32x4 zero = {0.f, 0.f, 0.f, 0.f};
    f32x4 acc[4][4];
    #pragma unroll
    for (int t = 0; t < 4; ++t)
        #pragma unroll
        for (int g = 0; g < 4; ++g) acc[t][g] = zero;

    for (int ks = 0; ks < 4; ++ks) {
        int kbase = ks * 32;
        __syncthreads();
        #pragma unroll
        for (int it = 0; it < 2; ++it) {
            int lin = it * TPB + tid;
            int row = lin >> 2, seg = lin & 3;
            int node = n0 + row;
            f32x4 v = zero;
            if (node < N) v = *(const f32x4*)(featb + (size_t)node * 128 + kbase + seg * 8);
            *(f32x4*)&Bs[row * 40 + seg * 8] = v;
        }
        __syncthreads();
        bf16x8 a[4], b[4];
        #pragma unroll
        for (int t = 0; t < 4; ++t)
            a[t] = *(const bf16x8*)(Ap + (((size_t)ks * 8 + w_p * 4 + t) * 64 + lane) * 8);
        #pragma unroll
        for (int g = 0; g < 4; ++g)
            b[g] = *(const bf16x8*)&Bs[(w_n * 64 + g * 16 + m16) * 40 + quad * 8];
        #pragma unroll
        for (int t = 0; t < 4; ++t)
            #pragma unroll
            for (int g = 0; g < 4; ++g)
                acc[t][g] = __builtin_amdgcn_mfma_f32_16x16x32_bf16(a[t], b[g], acc[t][g], 0, 0, 0);
    }
    #pragma unroll
    for (int t = 0; t < 4; ++t) {
        int p = w_p * 64 + t * 16 + quad * 4;
        f32x4 bv = *(const f32x4*)(bias + p);
        #pragma unroll
        for (int g = 0; g < 4; ++g) {
            int nd = n0 + w_n * 64 + g * 16 + m16;
            if (nd < N) {
                f32x4 o = acc[t][g] + bv;
                *(f32x4*)(Cout + (size_t)nd * 128 + p) = o;
            }
        }
    }
}

// ---------------- fused cell GEMM + LSTM gates (transposed, gate-packed) ----------------
// C'[p][node], p = jcol*4+gate, K=256 (ax | ah). Lane reg r = gate r of jcol.

__global__ __launch_bounds__(TPB) void k_cell_t(
        const __hip_bfloat16* __restrict__ Ap,     // packed [8][32][64][8] for this step
        const __hip_bfloat16* __restrict__ axb, const __hip_bfloat16* __restrict__ ahb,
        const float* __restrict__ bias,            // bcell + s*512
        float* __restrict__ cbuf, float* __restrict__ hout,
        float* __restrict__ hfin, int N) {
    __shared__ __align__(16) short Bs[128 * 40];
    int tid = threadIdx.x;
    int wave = tid >> 6, lane = tid & 63;
    int w_p = wave >> 1, w_n = wave & 1;
    int n0 = blockIdx.x * 128;
    int p0 = blockIdx.y * 128;
    int quad = lane >> 4, m16 = lane & 15;
    f32x4 zero = {0.f, 0.f, 0.f, 0.f};
    f32x4 acc[4][4];
    #pragma unroll
    for (int t = 0; t < 4; ++t)
        #pragma unroll
        for (int g = 0; g < 4; ++g) acc[t][g] = zero;

    for (int ks = 0; ks < 8; ++ks) {
        const __hip_bfloat16* fsrc = (ks < 4) ? axb : ahb;
        int kbase = (ks & 3) * 32;
        __syncthreads();
        #pragma unroll
        for (int it = 0; it < 2; ++it) {
            int lin = it * TPB + tid;
            int row = lin >> 2, seg = lin & 3;
            int node = n0 + row;
            f32x4 v = zero;
            if (node < N) v = *(const f32x4*)(fsrc + (size_t)node * 128 + kbase + seg * 8);
            *(f32x4*)&Bs[row * 40 + seg * 8] = v;
        }
        __syncthreads();
        bf16x8 a[4], b[4];
        #pragma unroll
        for (int t = 0; t < 4; ++t)
            a[t] = *(const bf16x8*)(Ap + (((size_t)ks * 32 + (p0 >> 4) + w_p * 4 + t) * 64 + lane) * 8);
        #pragma unroll
        for (int g = 0; g < 4; ++g)
            b[g] = *(const bf16x8*)&Bs[(w_n * 64 + g * 16 + m16) * 40 + quad * 8];
        #pragma unroll
        for (int t = 0; t < 4; ++t)
            #pragma unroll
            for (int g = 0; g < 4; ++g)
                acc[t][g] = __builtin_amdgcn_mfma_f32_16x16x32_bf16(a[t], b[g], acc[t][g], 0, 0, 0);
    }
    #pragma unroll
    for (int t = 0; t < 4; ++t) {
        int p = p0 + w_p * 64 + t * 16 + quad * 4;
        int jcol = p >> 2;
        float bf = bias[jcol], bi = bias[128 + jcol], bo = bias[256 + jcol], bg = bias[384 + jcol];
        #pragma unroll
        for (int g = 0; g < 4; ++g) {
            int nd = n0 + w_n * 64 + g * 16 + m16;
            if (nd < N) {
                float fv = sigf(acc[t][g].x + bf);
                float iv = sigf(acc[t][g].y + bi);
                float ov = sigf(acc[t][g].z + bo);
                float gv = tanhfast(acc[t][g].w + bg);
                size_t idx = (size_t)nd * 128 + jcol;
                float cp = cbuf[idx];
                float cn = fmaf(fv, cp, iv * gv);
                cbuf[idx] = cn;
                float hn = ov * tanhfast(cn);
                hout[idx] = hn;
                if (hfin) hfin[idx] = hn;
            }
        }
    }
}

// ---------------- launch ----------------

extern "C" void kernel_launch(void* const* d_in, const int* in_sizes, int n_in,
                              void* d_out, int out_size, void* d_ws, size_t ws_size,
                              hipStream_t stream) {
    const float* x  = (const float*)d_in[0];
    const float* c  = (const float*)d_in[1];
    const int*   ei = (const int*)d_in[2];
    const float* Wh = (const float*)d_in[3];
    const float* bh = (const float*)d_in[4];
    const float* Wc = (const float*)d_in[5];
    const float* bc = (const float*)d_in[6];
    const float* Wcell = (const float*)d_in[7];
    const float* bcell = (const float*)d_in[8];
    float* out = (float*)d_out;

    const int N = in_sizes[0] / 128;
    const int E = in_sizes[2] / 2;
    const int S = in_sizes[7] / (256 * 512);
    const int* srcp = ei;
    const int* dstp = ei + E;

    // output layout: hs [S,N,128] | h_fin [N,128] | c_fin [N,128]
    float* hs   = out;
    float* hfin = out + (size_t)S * N * 128;
    float* cbuf = hfin + (size_t)N * 128;

    char* w = (char*)d_ws;
    size_t off = 0;
    auto alloc = [&](size_t bytes) -> void* {
        void* p = w + off;
        off += (bytes + 255) & ~(size_t)255;
        return p;
    };
    int*   counts  = (int*)alloc((size_t)N * 4);
    int*   offsets = (int*)alloc((size_t)(N + 1) * 4);
    int*   cursor  = (int*)alloc((size_t)N * 4);
    int*   sums    = (int*)alloc(256 * 4);
    int*   csr_src = (int*)alloc((size_t)E * 4);
    float* csr_w   = (float*)alloc((size_t)E * 4);
    float* dinv    = (float*)alloc((size_t)N * 4);
    __hip_bfloat16* axb = (__hip_bfloat16*)alloc((size_t)N * 128 * 2);
    __hip_bfloat16* acb = (__hip_bfloat16*)alloc((size_t)N * 128 * 2);  // ac, then ah per step
    float* h0 = (float*)alloc((size_t)N * 128 * 4);
    __hip_bfloat16* WhP = (__hip_bfloat16*)alloc(16384 * 2);
    __hip_bfloat16* WcP = (__hip_bfloat16*)alloc(16384 * 2);
    __hip_bfloat16* WcellP = (__hip_bfloat16*)alloc((size_t)S * 131072 * 2);
    (void)ws_size; (void)n_in; (void)out_size;

    hipMemsetAsync(counts, 0, (size_t)N * 4, stream);
    int eblk = (E + TPB - 1) / TPB;
    int nb   = (N + TPB - 1) / TPB;
    k_hist<<<eblk, TPB, 0, stream>>>(dstp, counts, E);
    k_scan_block<<<nb, TPB, 0, stream>>>(counts, offsets, sums, N);
    k_scan_tops<<<1, TPB, 0, stream>>>(sums, nb);
    k_scan_finish<<<nb, TPB, 0, stream>>>(counts, offsets, sums, cursor, dinv, N, E);
    k_csr_scatter<<<eblk, TPB, 0, stream>>>(srcp, dstp, dinv, cursor, csr_src, csr_w, E);

    // pack weights to MFMA frag order (bf16)
    k_pack_w128<<<64, TPB, 0, stream>>>(Wh, WhP);
    k_pack_w128<<<64, TPB, 0, stream>>>(Wc, WcP);
    k_pack_wcell<<<(S * 131072 + TPB - 1) / TPB, TPB, 0, stream>>>(Wcell, WcellP, S);

    int nagg = (N + 3) / 4;
    int ngt  = (N + 127) / 128;
    k_aggregate_b<<<nagg, TPB, 0, stream>>>(x, axb, offsets, csr_src, csr_w, dinv, N);
    k_aggregate_b<<<nagg, TPB, 0, stream>>>(c, acb, offsets, csr_src, csr_w, dinv, N);
    k_gemm_t<<<ngt, TPB, 0, stream>>>(WhP, axb, bh, h0, N);
    k_gemm_t<<<ngt, TPB, 0, stream>>>(WcP, acb, bc, cbuf, N);

    for (int s = 0; s < S; ++s) {
        const float* hprev = (s == 0) ? h0 : hs + (size_t)(s - 1) * N * 128;
        k_aggregate_b<<<nagg, TPB, 0, stream>>>(hprev, acb, offsets, csr_src, csr_w, dinv, N);
        k_cell_t<<<dim3(ngt, 4), TPB, 0, stream>>>(
            WcellP + (size_t)s * 131072, axb, acb, bcell + (size_t)s * 512,
            cbuf, hs + (size_t)s * N * 128, (s == S - 1) ? hfin : nullptr, N);
    }
}